// Round 4
// baseline (2379.344 us; speedup 1.0000x reference)
//
#include <hip/hip_runtime.h>
#include <cstdint>
#include <cstddef>

#define SS 12
#define NN 16384
#define EE 262144
#define TT 3072          // SS*NN/BB

typedef _Float16 h2_t __attribute__((ext_vector_type(2)));
typedef short bf16x8 __attribute__((ext_vector_type(8)));
typedef float floatx4 __attribute__((ext_vector_type(4)));
typedef unsigned short ushortx8 __attribute__((ext_vector_type(8)));

// ---------- helpers ----------
__device__ __forceinline__ float fast_tanh(float x) {
    float e = __builtin_amdgcn_exp2f(2.885390082f * x);    // exp(2x); inf-safe
    return 1.f - 2.f * __builtin_amdgcn_rcpf(e + 1.f);
}
__device__ __forceinline__ unsigned short f2bf(float f) {
    unsigned int x = __float_as_uint(f);
    unsigned int r = (x + 0x7FFFu + ((x >> 16) & 1u)) >> 16;
    return (unsigned short)r;
}
__device__ __forceinline__ float bf2f(unsigned short u) {
    return __uint_as_float(((unsigned int)u) << 16);
}
// quad_perm(1,0,3,2): swap lane l ^ 1
__device__ __forceinline__ float dpp_xor1(float x) {
    int i = __builtin_amdgcn_mov_dpp(__float_as_int(x), 0xB1, 0xF, 0xF, true);
    return __int_as_float(i);
}
// quad_perm(2,3,0,1): swap lane l ^ 2
__device__ __forceinline__ float dpp_xor2(float x) {
    int i = __builtin_amdgcn_mov_dpp(__float_as_int(x), 0x4E, 0xF, 0xF, true);
    return __int_as_float(i);
}
// quad_perm(3,2,1,0): swap lane l ^ 3
__device__ __forceinline__ float dpp_xor3(float x) {
    int i = __builtin_amdgcn_mov_dpp(__float_as_int(x), 0x1B, 0xF, 0xF, true);
    return __int_as_float(i);
}

// ---------- zero counts ----------
__global__ void k_zero(int* __restrict__ p) {
    p[blockIdx.x * 256 + threadIdx.x] = 0;
}

// ---------- CSR build ----------
__global__ void k_count(const int* __restrict__ adj, int* __restrict__ counts) {
    int i = blockIdx.x * 256 + threadIdx.x;          // over SS*EE
    int t = i / EE, e = i - t * EE;
    int dst = adj[(size_t)t * 2 * EE + e];
    atomicAdd(&counts[t * NN + dst], 1);
}

__global__ void k_scan(const int* __restrict__ counts, int* __restrict__ offs,
                       int* __restrict__ cursor) {
    __shared__ int sums[1024];
    int t = blockIdx.x, tid = threadIdx.x;
    const int per = NN / 1024;                       // 16
    int base = t * NN + tid * per;
    int local[16];
    int s = 0;
#pragma unroll
    for (int i = 0; i < per; i++) { local[i] = counts[base + i]; s += local[i]; }
    sums[tid] = s;
    __syncthreads();
    for (int off = 1; off < 1024; off <<= 1) {
        int v = (tid >= off) ? sums[tid - off] : 0;
        __syncthreads();
        sums[tid] += v;
        __syncthreads();
    }
    int run = sums[tid] - s;                         // exclusive
#pragma unroll
    for (int i = 0; i < per; i++) { offs[base + i] = run; cursor[base + i] = run; run += local[i]; }
}

__global__ void k_scatter(const int* __restrict__ adj, const float* __restrict__ vals,
                          int* __restrict__ cursor, int2* __restrict__ edges) {
    int i = blockIdx.x * 256 + threadIdx.x;
    int t = i / EE, e = i - t * EE;
    int dst = adj[(size_t)t * 2 * EE + e];
    int src = adj[(size_t)t * 2 * EE + EE + e];
    float v = vals[(size_t)t * EE + e];
    int p = atomicAdd(&cursor[t * NN + dst], 1);
    edges[(size_t)t * EE + p] = make_int2(src, __float_as_int(v));
}

// ---------- support = xs @ gcn_weight  (fp32 acc, bf16 out) ----------
__global__ __launch_bounds__(256) void k_support(const float* __restrict__ xs,
                                                 const float* __restrict__ W,
                                                 unsigned short* __restrict__ sup) {
    __shared__ float Ash[64][128];
    __shared__ float Wsh[128][128];
    int tid = threadIdx.x;
    size_t rowbase = (size_t)blockIdx.x * 64;
    const float4* xa = (const float4*)(xs + rowbase * 128);
    float4* As = (float4*)&Ash[0][0];
#pragma unroll
    for (int q = 0; q < 8; q++) As[tid + q * 256] = xa[tid + q * 256];
    const float4* wg = (const float4*)W;
    float4* Ws = (float4*)&Wsh[0][0];
#pragma unroll
    for (int q = 0; q < 16; q++) Ws[tid + q * 256] = wg[tid + q * 256];
    __syncthreads();
    int jg = tid & 31, rg = tid >> 5;
    float acc[8][4];
#pragma unroll
    for (int i = 0; i < 8; i++)
#pragma unroll
        for (int j = 0; j < 4; j++) acc[i][j] = 0.f;
    for (int k4 = 0; k4 < 128; k4 += 4) {
        float4 a[8];
#pragma unroll
        for (int i = 0; i < 8; i++) a[i] = *(const float4*)&Ash[rg * 8 + i][k4];
#pragma unroll
        for (int kk = 0; kk < 4; kk++) {
            float4 wv = *(const float4*)&Wsh[k4 + kk][jg * 4];
#pragma unroll
            for (int i = 0; i < 8; i++) {
                float av = (kk == 0) ? a[i].x : (kk == 1) ? a[i].y : (kk == 2) ? a[i].z : a[i].w;
                acc[i][0] += av * wv.x; acc[i][1] += av * wv.y;
                acc[i][2] += av * wv.z; acc[i][3] += av * wv.w;
            }
        }
    }
#pragma unroll
    for (int i = 0; i < 8; i++) {
        ushort4 o;
        o.x = f2bf(acc[i][0]); o.y = f2bf(acc[i][1]);
        o.z = f2bf(acc[i][2]); o.w = f2bf(acc[i][3]);
        *(ushort4*)&sup[(rowbase + rg * 8 + i) * 128 + jg * 4] = o;
    }
}

// ---------- gather-reduce: wave per node, 2 dims per lane ----------
__global__ __launch_bounds__(256) void k_gather(const int2* __restrict__ edges,
                         const int* __restrict__ offs,
                         const int* __restrict__ ends,
                         const unsigned short* __restrict__ sup,
                         const float* __restrict__ bias,
                         unsigned short* __restrict__ cur) {
    int bn = blockIdx.x * 4 + (threadIdx.x >> 6);     // t*NN + n, wave-uniform
    bn = __builtin_amdgcn_readfirstlane(bn);
    int t = bn >> 14;
    int l = threadIdx.x & 63;
    int beg = offs[bn];
    int end = ends[bn];
    const unsigned short* supt = sup + (size_t)t * NN * 128;
    const int2* eg = edges + (size_t)t * EE;
    float acc0 = 0.f, acc1 = 0.f;                     // dims 2l, 2l+1
    int p = beg;
    for (; p + 3 < end; p += 4) {
        int2 e0 = eg[p], e1 = eg[p + 1], e2 = eg[p + 2], e3 = eg[p + 3];
        unsigned int u0 = *(const unsigned int*)&supt[(size_t)e0.x * 128 + 2 * l];
        unsigned int u1 = *(const unsigned int*)&supt[(size_t)e1.x * 128 + 2 * l];
        unsigned int u2 = *(const unsigned int*)&supt[(size_t)e2.x * 128 + 2 * l];
        unsigned int u3 = *(const unsigned int*)&supt[(size_t)e3.x * 128 + 2 * l];
        float w0 = __int_as_float(e0.y), w1 = __int_as_float(e1.y);
        float w2 = __int_as_float(e2.y), w3 = __int_as_float(e3.y);
        acc0 += w0 * bf2f((unsigned short)u0); acc1 += w0 * bf2f((unsigned short)(u0 >> 16));
        acc0 += w1 * bf2f((unsigned short)u1); acc1 += w1 * bf2f((unsigned short)(u1 >> 16));
        acc0 += w2 * bf2f((unsigned short)u2); acc1 += w2 * bf2f((unsigned short)(u2 >> 16));
        acc0 += w3 * bf2f((unsigned short)u3); acc1 += w3 * bf2f((unsigned short)(u3 >> 16));
    }
    for (; p < end; p++) {
        int2 e0 = eg[p];
        unsigned int u0 = *(const unsigned int*)&supt[(size_t)e0.x * 128 + 2 * l];
        float w0 = __int_as_float(e0.y);
        acc0 += w0 * bf2f((unsigned short)u0);
        acc1 += w0 * bf2f((unsigned short)(u0 >> 16));
    }
    float r0 = acc0 + bias[2 * l];
    float r1 = acc1 + bias[2 * l + 1];
    ushort2 o;
    o.x = f2bf(r0 > 0.f ? r0 : 0.f);
    o.y = f2bf(r1 > 0.f ? r1 : 0.f);
    *(ushort2*)&cur[(size_t)bn * 128 + 2 * l] = o;
}

// ---------- gates_x = cur @ w_ih^T + (b_ih+b_hh), bf16 MFMA ----------
// grid (3072, 8), 256 thr. Block: rows 64 (M), gates 64 (N), K=128.
// Output layout for k_lstm: element j's 4 gates (i,f,g,o) contiguous:
//   slot = j*4 + gate_idx   (gate_idx = gcol>>7, j = gcol&127)
// so k_lstm thread tid (= j*4+g) does ONE aligned 2B load per step.
__global__ __launch_bounds__(256) void k_xgates(const unsigned short* __restrict__ cur,
                                                const float* __restrict__ wih,
                                                const float* __restrict__ bih,
                                                const float* __restrict__ bhh,
                                                unsigned short* __restrict__ gx) {
    __shared__ __align__(16) unsigned short At[64][136];   // +8 pad: 2-way banks
    __shared__ __align__(16) unsigned short Bt[64][136];
    int tid = threadIdx.x;
    size_t rowbase = (size_t)blockIdx.x * 64;
    int gbase = blockIdx.y * 64;
    // A tile: 64x128 bf16, 16B chunks
#pragma unroll
    for (int q = 0; q < 4; q++) {
        int idx = tid + q * 256;          // 0..1023 (16 chunks per row)
        int r = idx >> 4;
        int cc = (idx & 15) * 8;
        *(ushortx8*)&At[r][cc] = *(const ushortx8*)&cur[(rowbase + r) * 128 + cc];
    }
    // B tile: wih rows gbase..gbase+64, fp32 -> bf16 on the fly
#pragma unroll
    for (int q = 0; q < 8; q++) {
        int idx = tid + q * 256;          // 0..2047 (32 float4 per row)
        int r = idx >> 5;
        int c4 = (idx & 31) * 4;
        float4 v = *(const float4*)&wih[(size_t)(gbase + r) * 128 + c4];
        ushort4 o;
        o.x = f2bf(v.x); o.y = f2bf(v.y); o.z = f2bf(v.z); o.w = f2bf(v.w);
        *(ushort4*)&Bt[r][c4] = o;
    }
    __syncthreads();
    int wave = tid >> 6, lane = tid & 63;
    int m0 = wave * 16;
    int rin = lane & 15;
    int koff = (lane >> 4) * 8;
    floatx4 acc[4];
#pragma unroll
    for (int n = 0; n < 4; n++) acc[n] = (floatx4){0.f, 0.f, 0.f, 0.f};
#pragma unroll
    for (int kc = 0; kc < 4; kc++) {
        bf16x8 a = *(const bf16x8*)&At[m0 + rin][kc * 32 + koff];
#pragma unroll
        for (int n = 0; n < 4; n++) {
            bf16x8 b = *(const bf16x8*)&Bt[n * 16 + rin][kc * 32 + koff];
            acc[n] = __builtin_amdgcn_mfma_f32_16x16x32_bf16(a, b, acc[n], 0, 0, 0);
        }
    }
    // C/D: col = lane&15, row = (lane>>4)*4 + reg
    int rq = (lane >> 4) * 4;
#pragma unroll
    for (int n = 0; n < 4; n++) {
        int gcol = gbase + n * 16 + rin;
        float bs = bih[gcol] + bhh[gcol];
        int slot = ((gcol & 127) << 2) | (gcol >> 7);
#pragma unroll
        for (int i = 0; i < 4; i++) {
            size_t row = rowbase + m0 + rq + i;
            gx[row * 512 + slot] = f2bf(acc[n][i] + bs);
        }
    }
}

// ---------- persistent LSTM: 64 blocks x 512 thr (8 waves, 2/SIMD) --------
// Quad j = tid>>2 owns hidden element j. Lane q = tid&3 owns BOTH the
// K-quarter [32q,32q+32) of h AND gate q (torch order: 0=i,1=f,2=g,3=o).
// Per step: 64 fdot2 (4 gate-chains x 16) -> 2-stage DPP butterfly gives
// every lane all 4 full gate sums -> each lane activates ONLY its own gate
// (2 trans ops; tanh via affine-sigmoid trick, branchless per-lane consts)
// -> lane q=0 collects the 4 activated gates via 3 quad_perm DPPs
// (xor1/xor2/xor3) and updates c,h. 2 waves/SIMD hide LDS/trans stalls.
// gx slot = j*4+q = tid: scalar ushort ring, 3 deep. h double-buffered in
// LDS: ONE barrier per step. out stored in bursts of 8 steps.
__global__ __launch_bounds__(512, 2) void k_lstm(const unsigned short* __restrict__ gx,
                                                 const float* __restrict__ whh,
                                                 const float* __restrict__ h0,
                                                 const float* __restrict__ c0,
                                                 float* __restrict__ out) {
    __shared__ __align__(16) _Float16 hsh[2][128];   // double-buffered h (f16)
    int b = blockIdx.x, tid = threadIdx.x;
    int j = tid >> 2;                 // element 0..127
    int q = tid & 3;                  // gate & K-quarter role
    // own-gate activation: act = Aa * sig(Ss*x) + Bb  (q==2 -> tanh)
    float K1 = (q == 2) ? -2.885390082f : -1.442695041f;   // exp2 coeff
    float Aa = (q == 2) ? 2.f : 1.f;
    float Bb = (q == 2) ? -1.f : 0.f;

    // weights: w[g][16] h2 = rows g*128+j, cols [32q, 32q+32)   (64 VGPRs)
    h2_t w[4][16];
#pragma unroll
    for (int g = 0; g < 4; g++) {
        const float4* rp = (const float4*)(whh + (size_t)(g * 128 + j) * 128 + q * 32);
#pragma unroll
        for (int q4 = 0; q4 < 8; q4++) {
            float4 v = rp[q4];
            h2_t a; a.x = (_Float16)v.x; a.y = (_Float16)v.y;
            h2_t bq; bq.x = (_Float16)v.z; bq.y = (_Float16)v.w;
            w[g][2 * q4] = a; w[g][2 * q4 + 1] = bq;
        }
    }
    float c = c0[(size_t)b * 128 + j];               // only q==0's copy stays valid
    if (tid < 128) hsh[0][tid] = (_Float16)h0[(size_t)b * 128 + tid];
    __syncthreads();

    // gx ring: one 2B value per thread per step, 3 deep (slot == tid)
    const unsigned short* gxb = gx + (size_t)b * 512 + tid;
    unsigned short rg0 = gxb[0];
    unsigned short rg1 = gxb[32768];
    unsigned short rg2 = gxb[2 * (size_t)32768];

#define LSTM_STEP(T, RD, WR, QIDX)                                          \
    {                                                                       \
        const h2_t* hp_ = (const h2_t*)&hsh[RD][32 * q];                    \
        h2_t hs_[16];                                                       \
        _Pragma("unroll")                                                   \
        for (int kk = 0; kk < 16; kk++) hs_[kk] = hp_[kk];                  \
        float part_[4];                                                     \
        _Pragma("unroll")                                                   \
        for (int g = 0; g < 4; g++) part_[g] = 0.f;                         \
        _Pragma("unroll")                                                   \
        for (int kk = 0; kk < 16; kk++) {                                   \
            _Pragma("unroll")                                               \
            for (int g = 0; g < 4; g++)                                     \
                part_[g] = __builtin_amdgcn_fdot2(w[g][kk], hs_[kk],        \
                                                  part_[g], false);         \
        }                                                                   \
        _Pragma("unroll")                                                   \
        for (int g = 0; g < 4; g++) part_[g] += dpp_xor1(part_[g]);         \
        _Pragma("unroll")                                                   \
        for (int g = 0; g < 4; g++) part_[g] += dpp_xor2(part_[g]);         \
        float s01_ = (q & 1) ? part_[1] : part_[0];                         \
        float s23_ = (q & 1) ? part_[3] : part_[2];                         \
        float sown_ = (q & 2) ? s23_ : s01_;                                \
        float x_ = sown_ + bf2f(rg0);                                       \
        float e_ = __builtin_amdgcn_exp2f(K1 * x_);                         \
        float act_ = Aa * __builtin_amdgcn_rcpf(1.f + e_) + Bb;             \
        float f_ = dpp_xor1(act_);                                          \
        float tg_ = dpp_xor2(act_);                                         \
        float o_ = dpp_xor3(act_);                                          \
        c = f_ * c + act_ * tg_;      /* valid on q==0 lanes */             \
        float hn_ = o_ * fast_tanh(c);                                      \
        hh8[QIDX] = hn_;                                                    \
        if (q == 0) hsh[WR][j] = (_Float16)hn_;                             \
        rg0 = rg1; rg1 = rg2;                                               \
        {                                                                   \
            int tp_ = ((T) + 3 < TT) ? (T) + 3 : TT - 1;                    \
            rg2 = gxb[(size_t)tp_ * 32768];                                 \
        }                                                                   \
        __syncthreads();                                                    \
    }

    for (int t8 = 0; t8 < TT; t8 += 8) {
        float hh8[8];
        LSTM_STEP(t8 + 0, 0, 1, 0);
        LSTM_STEP(t8 + 1, 1, 0, 1);
        LSTM_STEP(t8 + 2, 0, 1, 2);
        LSTM_STEP(t8 + 3, 1, 0, 3);
        LSTM_STEP(t8 + 4, 0, 1, 4);
        LSTM_STEP(t8 + 5, 1, 0, 5);
        LSTM_STEP(t8 + 6, 0, 1, 6);
        LSTM_STEP(t8 + 7, 1, 0, 7);
        if (q == 0) {
#pragma unroll
            for (int qq = 0; qq < 8; qq++)
                out[((size_t)(t8 + qq) * 64 + b) * 128 + j] = hh8[qq];
        }
    }
#undef LSTM_STEP
}

// ---------- launcher ----------
extern "C" void kernel_launch(void* const* d_in, const int* in_sizes, int n_in,
                              void* d_out, int out_size, void* d_ws, size_t ws_size,
                              hipStream_t stream) {
    const int* adj    = (const int*)d_in[0];
    const float* vals = (const float*)d_in[1];
    const float* xs   = (const float*)d_in[2];
    const float* gw   = (const float*)d_in[3];
    const float* gb   = (const float*)d_in[4];
    const float* wih  = (const float*)d_in[5];
    const float* whh  = (const float*)d_in[6];
    const float* bih  = (const float*)d_in[7];
    const float* bhh  = (const float*)d_in[8];
    const float* h0   = (const float*)d_in[9];
    const float* c0   = (const float*)d_in[10];
    float* out = (float*)d_out;

    // Workspace layout (peak concurrent = 251,658,240 B):
    //   [0, 50,331,648)             cur (bf16, S*N*128)
    //   [50,331,648, 251,658,240)   gx  (bf16, S*N*512)
    // Aliased INSIDE the gx region (dead before k_xgates writes gx):
    //   support @ gx+0, counts/offs/cursor/edges after it.
    char* ws = (char*)d_ws;
    unsigned short* cur = (unsigned short*)(ws);
    unsigned short* gx  = (unsigned short*)(ws + 50331648);
    unsigned short* sup = (unsigned short*)(ws + 50331648);
    int* counts         = (int*)(ws + 100663296);
    int* offs           = (int*)(ws + 101449728);
    int* cursor         = (int*)(ws + 102236160);
    int2* edges         = (int2*)(ws + 103022592);

    k_zero<<<(SS * NN) / 256, 256, 0, stream>>>(counts);
    k_count<<<(SS * EE) / 256, 256, 0, stream>>>(adj, counts);
    k_scan<<<SS, 1024, 0, stream>>>(counts, offs, cursor);
    k_scatter<<<(SS * EE) / 256, 256, 0, stream>>>(adj, vals, cursor, edges);
    k_support<<<(SS * NN) / 64, 256, 0, stream>>>(xs, gw, sup);
    k_gather<<<(SS * NN) / 4, 256, 0, stream>>>(edges, offs, cursor, sup, gb, cur);
    k_xgates<<<dim3((SS * NN) / 64, 8), 256, 0, stream>>>(cur, wih, bih, bhh, gx);
    k_lstm<<<64, 512, 0, stream>>>(gx, whh, h0, c0, out);
}

// Round 5
// 2290.805 us; speedup vs baseline: 1.0386x; 1.0386x over previous
//
#include <hip/hip_runtime.h>
#include <cstdint>
#include <cstddef>

#define SS 12
#define NN 16384
#define EE 262144
#define TT 3072          // SS*NN/BB

typedef _Float16 h2_t __attribute__((ext_vector_type(2)));
typedef _Float16 f16x8 __attribute__((ext_vector_type(8)));
typedef short bf16x8 __attribute__((ext_vector_type(8)));
typedef float floatx4 __attribute__((ext_vector_type(4)));
typedef unsigned short ushortx8 __attribute__((ext_vector_type(8)));

// ---------- helpers ----------
__device__ __forceinline__ float fast_sig(float x) {
    float e = __builtin_amdgcn_exp2f(-1.442695041f * x);   // exp(-x)
    return __builtin_amdgcn_rcpf(1.f + e);
}
__device__ __forceinline__ float fast_tanh(float x) {
    float e = __builtin_amdgcn_exp2f(2.885390082f * x);    // exp(2x); inf-safe
    return 1.f - 2.f * __builtin_amdgcn_rcpf(e + 1.f);
}
__device__ __forceinline__ unsigned short f2bf(float f) {
    unsigned int x = __float_as_uint(f);
    unsigned int r = (x + 0x7FFFu + ((x >> 16) & 1u)) >> 16;
    return (unsigned short)r;
}
__device__ __forceinline__ float bf2f(unsigned short u) {
    return __uint_as_float(((unsigned int)u) << 16);
}

// ---------- zero counts ----------
__global__ void k_zero(int* __restrict__ p) {
    p[blockIdx.x * 256 + threadIdx.x] = 0;
}

// ---------- CSR build ----------
__global__ void k_count(const int* __restrict__ adj, int* __restrict__ counts) {
    int i = blockIdx.x * 256 + threadIdx.x;          // over SS*EE
    int t = i / EE, e = i - t * EE;
    int dst = adj[(size_t)t * 2 * EE + e];
    atomicAdd(&counts[t * NN + dst], 1);
}

__global__ void k_scan(const int* __restrict__ counts, int* __restrict__ offs,
                       int* __restrict__ cursor) {
    __shared__ int sums[1024];
    int t = blockIdx.x, tid = threadIdx.x;
    const int per = NN / 1024;                       // 16
    int base = t * NN + tid * per;
    int local[16];
    int s = 0;
#pragma unroll
    for (int i = 0; i < per; i++) { local[i] = counts[base + i]; s += local[i]; }
    sums[tid] = s;
    __syncthreads();
    for (int off = 1; off < 1024; off <<= 1) {
        int v = (tid >= off) ? sums[tid - off] : 0;
        __syncthreads();
        sums[tid] += v;
        __syncthreads();
    }
    int run = sums[tid] - s;                         // exclusive
#pragma unroll
    for (int i = 0; i < per; i++) { offs[base + i] = run; cursor[base + i] = run; run += local[i]; }
}

__global__ void k_scatter(const int* __restrict__ adj, const float* __restrict__ vals,
                          int* __restrict__ cursor, int2* __restrict__ edges) {
    int i = blockIdx.x * 256 + threadIdx.x;
    int t = i / EE, e = i - t * EE;
    int dst = adj[(size_t)t * 2 * EE + e];
    int src = adj[(size_t)t * 2 * EE + EE + e];
    float v = vals[(size_t)t * EE + e];
    int p = atomicAdd(&cursor[t * NN + dst], 1);
    edges[(size_t)t * EE + p] = make_int2(src, __float_as_int(v));
}

// ---------- support = xs @ gcn_weight  (fp32 acc, bf16 out) ----------
__global__ __launch_bounds__(256) void k_support(const float* __restrict__ xs,
                                                 const float* __restrict__ W,
                                                 unsigned short* __restrict__ sup) {
    __shared__ float Ash[64][128];
    __shared__ float Wsh[128][128];
    int tid = threadIdx.x;
    size_t rowbase = (size_t)blockIdx.x * 64;
    const float4* xa = (const float4*)(xs + rowbase * 128);
    float4* As = (float4*)&Ash[0][0];
#pragma unroll
    for (int q = 0; q < 8; q++) As[tid + q * 256] = xa[tid + q * 256];
    const float4* wg = (const float4*)W;
    float4* Ws = (float4*)&Wsh[0][0];
#pragma unroll
    for (int q = 0; q < 16; q++) Ws[tid + q * 256] = wg[tid + q * 256];
    __syncthreads();
    int jg = tid & 31, rg = tid >> 5;
    float acc[8][4];
#pragma unroll
    for (int i = 0; i < 8; i++)
#pragma unroll
        for (int j = 0; j < 4; j++) acc[i][j] = 0.f;
    for (int k4 = 0; k4 < 128; k4 += 4) {
        float4 a[8];
#pragma unroll
        for (int i = 0; i < 8; i++) a[i] = *(const float4*)&Ash[rg * 8 + i][k4];
#pragma unroll
        for (int kk = 0; kk < 4; kk++) {
            float4 wv = *(const float4*)&Wsh[k4 + kk][jg * 4];
#pragma unroll
            for (int i = 0; i < 8; i++) {
                float av = (kk == 0) ? a[i].x : (kk == 1) ? a[i].y : (kk == 2) ? a[i].z : a[i].w;
                acc[i][0] += av * wv.x; acc[i][1] += av * wv.y;
                acc[i][2] += av * wv.z; acc[i][3] += av * wv.w;
            }
        }
    }
#pragma unroll
    for (int i = 0; i < 8; i++) {
        ushort4 o;
        o.x = f2bf(acc[i][0]); o.y = f2bf(acc[i][1]);
        o.z = f2bf(acc[i][2]); o.w = f2bf(acc[i][3]);
        *(ushort4*)&sup[(rowbase + rg * 8 + i) * 128 + jg * 4] = o;
    }
}

// ---------- gather-reduce: wave per node, 2 dims per lane ----------
__global__ __launch_bounds__(256) void k_gather(const int2* __restrict__ edges,
                         const int* __restrict__ offs,
                         const int* __restrict__ ends,
                         const unsigned short* __restrict__ sup,
                         const float* __restrict__ bias,
                         unsigned short* __restrict__ cur) {
    int bn = blockIdx.x * 4 + (threadIdx.x >> 6);     // t*NN + n, wave-uniform
    bn = __builtin_amdgcn_readfirstlane(bn);
    int t = bn >> 14;
    int l = threadIdx.x & 63;
    int beg = offs[bn];
    int end = ends[bn];
    const unsigned short* supt = sup + (size_t)t * NN * 128;
    const int2* eg = edges + (size_t)t * EE;
    float acc0 = 0.f, acc1 = 0.f;                     // dims 2l, 2l+1
    int p = beg;
    for (; p + 3 < end; p += 4) {
        int2 e0 = eg[p], e1 = eg[p + 1], e2 = eg[p + 2], e3 = eg[p + 3];
        unsigned int u0 = *(const unsigned int*)&supt[(size_t)e0.x * 128 + 2 * l];
        unsigned int u1 = *(const unsigned int*)&supt[(size_t)e1.x * 128 + 2 * l];
        unsigned int u2 = *(const unsigned int*)&supt[(size_t)e2.x * 128 + 2 * l];
        unsigned int u3 = *(const unsigned int*)&supt[(size_t)e3.x * 128 + 2 * l];
        float w0 = __int_as_float(e0.y), w1 = __int_as_float(e1.y);
        float w2 = __int_as_float(e2.y), w3 = __int_as_float(e3.y);
        acc0 += w0 * bf2f((unsigned short)u0); acc1 += w0 * bf2f((unsigned short)(u0 >> 16));
        acc0 += w1 * bf2f((unsigned short)u1); acc1 += w1 * bf2f((unsigned short)(u1 >> 16));
        acc0 += w2 * bf2f((unsigned short)u2); acc1 += w2 * bf2f((unsigned short)(u2 >> 16));
        acc0 += w3 * bf2f((unsigned short)u3); acc1 += w3 * bf2f((unsigned short)(u3 >> 16));
    }
    for (; p < end; p++) {
        int2 e0 = eg[p];
        unsigned int u0 = *(const unsigned int*)&supt[(size_t)e0.x * 128 + 2 * l];
        float w0 = __int_as_float(e0.y);
        acc0 += w0 * bf2f((unsigned short)u0);
        acc1 += w0 * bf2f((unsigned short)(u0 >> 16));
    }
    float r0 = acc0 + bias[2 * l];
    float r1 = acc1 + bias[2 * l + 1];
    ushort2 o;
    o.x = f2bf(r0 > 0.f ? r0 : 0.f);
    o.y = f2bf(r1 > 0.f ? r1 : 0.f);
    *(ushort2*)&cur[(size_t)bn * 128 + 2 * l] = o;
}

// ---------- gates_x = cur @ w_ih^T + (b_ih+b_hh), bf16 MFMA ----------
// grid (3072, 8), 256 thr. Block: rows 64 (M), gates 64 (N), K=128.
// Output layout for k_lstm: element j's 4 gates (i,f,g,o) contiguous:
//   slot = j*4 + gate_idx   (gate_idx = gcol>>7, j = gcol&127)
__global__ __launch_bounds__(256) void k_xgates(const unsigned short* __restrict__ cur,
                                                const float* __restrict__ wih,
                                                const float* __restrict__ bih,
                                                const float* __restrict__ bhh,
                                                unsigned short* __restrict__ gx) {
    __shared__ __align__(16) unsigned short At[64][136];   // +8 pad: 2-way banks
    __shared__ __align__(16) unsigned short Bt[64][136];
    int tid = threadIdx.x;
    size_t rowbase = (size_t)blockIdx.x * 64;
    int gbase = blockIdx.y * 64;
    // A tile: 64x128 bf16, 16B chunks
#pragma unroll
    for (int q = 0; q < 4; q++) {
        int idx = tid + q * 256;          // 0..1023 (16 chunks per row)
        int r = idx >> 4;
        int cc = (idx & 15) * 8;
        *(ushortx8*)&At[r][cc] = *(const ushortx8*)&cur[(rowbase + r) * 128 + cc];
    }
    // B tile: wih rows gbase..gbase+64, fp32 -> bf16 on the fly
#pragma unroll
    for (int q = 0; q < 8; q++) {
        int idx = tid + q * 256;          // 0..2047 (32 float4 per row)
        int r = idx >> 5;
        int c4 = (idx & 31) * 4;
        float4 v = *(const float4*)&wih[(size_t)(gbase + r) * 128 + c4];
        ushort4 o;
        o.x = f2bf(v.x); o.y = f2bf(v.y); o.z = f2bf(v.z); o.w = f2bf(v.w);
        *(ushort4*)&Bt[r][c4] = o;
    }
    __syncthreads();
    int wave = tid >> 6, lane = tid & 63;
    int m0 = wave * 16;
    int rin = lane & 15;
    int koff = (lane >> 4) * 8;
    floatx4 acc[4];
#pragma unroll
    for (int n = 0; n < 4; n++) acc[n] = (floatx4){0.f, 0.f, 0.f, 0.f};
#pragma unroll
    for (int kc = 0; kc < 4; kc++) {
        bf16x8 a = *(const bf16x8*)&At[m0 + rin][kc * 32 + koff];
#pragma unroll
        for (int n = 0; n < 4; n++) {
            bf16x8 b = *(const bf16x8*)&Bt[n * 16 + rin][kc * 32 + koff];
            acc[n] = __builtin_amdgcn_mfma_f32_16x16x32_bf16(a, b, acc[n], 0, 0, 0);
        }
    }
    // C/D: col = lane&15, row = (lane>>4)*4 + reg
    int rq = (lane >> 4) * 4;
#pragma unroll
    for (int n = 0; n < 4; n++) {
        int gcol = gbase + n * 16 + rin;
        float bs = bih[gcol] + bhh[gcol];
        int slot = ((gcol & 127) << 2) | (gcol >> 7);
#pragma unroll
        for (int i = 0; i < 4; i++) {
            size_t row = rowbase + m0 + rq + i;
            gx[row * 512 + slot] = f2bf(acc[n][i] + bs);
        }
    }
}

// ---------- persistent LSTM: 64 blocks x 512 thr, MFMA recurrent matvec ----
// Per step per block: gates_h[512] = h[128] @ whh^T via v_mfma_f32_16x16x32_f16.
// Wave w owns elements [w*16, w*16+16). N-tile n = gate-type n (i,f,g,o) of
// those 16 elements; K split in 4 tiles of 32.
//   A (h) BROADCAST: every lane loads the same h k-slice (ds_read_b128,
//     same addr within each 16-lane group -> LDS broadcast). All 16 D-rows
//     are then identical, so EVERY lane's acc[n][0] is the gate-n sum for
//     its own column (lane&15). No cross-lane redistribution needed.
//   B (weights) preloaded once: lane holds whh[n*128 + w*16 + col][k-slice]
//     as f16x8; 16 fragments = 64 VGPRs.
//   k-map robustness: A and B use the same (lane,i)->k map, so the dot is
//     invariant to the HW k permutation; only col=lane&15 matters (verified
//     by k_xgates passing).
// Activations fully in-lane (acc[0..3][0] = i,f,g,o sums); c kept in-register
// (x4 redundant across k-groups); lanes 0-15 of each wave write h (f16, LDS
// double-buffered) and out. ONE barrier per step. gx slot=j*4+g: uint2 ring
// 3 deep. f16 inputs + f32 MFMA acc == numerics of the old fdot2 path.
__global__ __launch_bounds__(512, 2) void k_lstm(const unsigned short* __restrict__ gx,
                                                 const float* __restrict__ whh,
                                                 const float* __restrict__ h0,
                                                 const float* __restrict__ c0,
                                                 float* __restrict__ out) {
    __shared__ __align__(16) _Float16 hsh[2][128];   // double-buffered h (f16)
    int b = blockIdx.x, tid = threadIdx.x;
    int w = tid >> 6;                 // wave 0..7
    int l = tid & 63;
    int col = l & 15;                 // element within wave's 16
    int kg = l >> 4;                  // k-group 0..3 (8 k each per K-tile)
    int j = w * 16 + col;             // owned element (x4 redundant over kg)

    // B fragments: bw[n][kt], row = n*128 + j, k = kt*32 + kg*8 + i
    f16x8 bw[4][4];
#pragma unroll
    for (int n = 0; n < 4; n++) {
        const float* rp = whh + (size_t)(n * 128 + j) * 128;
#pragma unroll
        for (int kt = 0; kt < 4; kt++) {
            int k0 = kt * 32 + kg * 8;
            float4 v0 = *(const float4*)(rp + k0);
            float4 v1 = *(const float4*)(rp + k0 + 4);
            f16x8 f;
            f[0] = (_Float16)v0.x; f[1] = (_Float16)v0.y;
            f[2] = (_Float16)v0.z; f[3] = (_Float16)v0.w;
            f[4] = (_Float16)v1.x; f[5] = (_Float16)v1.y;
            f[6] = (_Float16)v1.z; f[7] = (_Float16)v1.w;
            bw[n][kt] = f;
        }
    }
    float c = c0[(size_t)b * 128 + j];               // redundant across kg
    if (tid < 128) hsh[0][tid] = (_Float16)h0[(size_t)b * 128 + tid];
    __syncthreads();

    // gx ring: one uint2 (4 bf16: i,f,g,o of element j) per step, 3 deep
    const unsigned short* gxb = gx + (size_t)b * 512 + 4 * j;
    uint2 rg0 = *(const uint2*)(gxb);
    uint2 rg1 = *(const uint2*)(gxb + 32768);
    uint2 rg2 = *(const uint2*)(gxb + 2 * (size_t)32768);

#define LSTM_STEP(T, RD, WR, QIDX)                                          \
    {                                                                       \
        f16x8 a0_ = *(const f16x8*)&hsh[RD][kg * 8];                        \
        f16x8 a1_ = *(const f16x8*)&hsh[RD][32 + kg * 8];                   \
        f16x8 a2_ = *(const f16x8*)&hsh[RD][64 + kg * 8];                   \
        f16x8 a3_ = *(const f16x8*)&hsh[RD][96 + kg * 8];                   \
        floatx4 ac0 = (floatx4){0.f, 0.f, 0.f, 0.f};                        \
        floatx4 ac1 = (floatx4){0.f, 0.f, 0.f, 0.f};                        \
        floatx4 ac2 = (floatx4){0.f, 0.f, 0.f, 0.f};                        \
        floatx4 ac3 = (floatx4){0.f, 0.f, 0.f, 0.f};                        \
        ac0 = __builtin_amdgcn_mfma_f32_16x16x32_f16(a0_, bw[0][0], ac0, 0, 0, 0); \
        ac1 = __builtin_amdgcn_mfma_f32_16x16x32_f16(a0_, bw[1][0], ac1, 0, 0, 0); \
        ac2 = __builtin_amdgcn_mfma_f32_16x16x32_f16(a0_, bw[2][0], ac2, 0, 0, 0); \
        ac3 = __builtin_amdgcn_mfma_f32_16x16x32_f16(a0_, bw[3][0], ac3, 0, 0, 0); \
        ac0 = __builtin_amdgcn_mfma_f32_16x16x32_f16(a1_, bw[0][1], ac0, 0, 0, 0); \
        ac1 = __builtin_amdgcn_mfma_f32_16x16x32_f16(a1_, bw[1][1], ac1, 0, 0, 0); \
        ac2 = __builtin_amdgcn_mfma_f32_16x16x32_f16(a1_, bw[2][1], ac2, 0, 0, 0); \
        ac3 = __builtin_amdgcn_mfma_f32_16x16x32_f16(a1_, bw[3][1], ac3, 0, 0, 0); \
        ac0 = __builtin_amdgcn_mfma_f32_16x16x32_f16(a2_, bw[0][2], ac0, 0, 0, 0); \
        ac1 = __builtin_amdgcn_mfma_f32_16x16x32_f16(a2_, bw[1][2], ac1, 0, 0, 0); \
        ac2 = __builtin_amdgcn_mfma_f32_16x16x32_f16(a2_, bw[2][2], ac2, 0, 0, 0); \
        ac3 = __builtin_amdgcn_mfma_f32_16x16x32_f16(a2_, bw[3][2], ac3, 0, 0, 0); \
        ac0 = __builtin_amdgcn_mfma_f32_16x16x32_f16(a3_, bw[0][3], ac0, 0, 0, 0); \
        ac1 = __builtin_amdgcn_mfma_f32_16x16x32_f16(a3_, bw[1][3], ac1, 0, 0, 0); \
        ac2 = __builtin_amdgcn_mfma_f32_16x16x32_f16(a3_, bw[2][3], ac2, 0, 0, 0); \
        ac3 = __builtin_amdgcn_mfma_f32_16x16x32_f16(a3_, bw[3][3], ac3, 0, 0, 0); \
        float ri_ = ac0[0] + bf2f((unsigned short)(rg0.x & 0xffffu));       \
        float rf_ = ac1[0] + bf2f((unsigned short)(rg0.x >> 16));           \
        float rg_ = ac2[0] + bf2f((unsigned short)(rg0.y & 0xffffu));       \
        float ro_ = ac3[0] + bf2f((unsigned short)(rg0.y >> 16));           \
        float ai_ = fast_sig(ri_);                                          \
        float af_ = fast_sig(rf_);                                          \
        float ag_ = fast_tanh(rg_);                                         \
        float ao_ = fast_sig(ro_);                                          \
        c = af_ * c + ai_ * ag_;                                            \
        float hn_ = ao_ * fast_tanh(c);                                     \
        hh8[QIDX] = hn_;                                                    \
        if (kg == 0) hsh[WR][j] = (_Float16)hn_;                            \
        rg0 = rg1; rg1 = rg2;                                               \
        {                                                                   \
            int tp_ = ((T) + 3 < TT) ? (T) + 3 : TT - 1;                    \
            rg2 = *(const uint2*)(gxb + (size_t)tp_ * 32768);               \
        }                                                                   \
        __syncthreads();                                                    \
    }

    for (int t8 = 0; t8 < TT; t8 += 8) {
        float hh8[8];
        LSTM_STEP(t8 + 0, 0, 1, 0);
        LSTM_STEP(t8 + 1, 1, 0, 1);
        LSTM_STEP(t8 + 2, 0, 1, 2);
        LSTM_STEP(t8 + 3, 1, 0, 3);
        LSTM_STEP(t8 + 4, 0, 1, 4);
        LSTM_STEP(t8 + 5, 1, 0, 5);
        LSTM_STEP(t8 + 6, 0, 1, 6);
        LSTM_STEP(t8 + 7, 1, 0, 7);
        if (kg == 0) {
#pragma unroll
            for (int qq = 0; qq < 8; qq++)
                out[((size_t)(t8 + qq) * 64 + b) * 128 + j] = hh8[qq];
        }
    }
#undef LSTM_STEP
}

// ---------- launcher ----------
extern "C" void kernel_launch(void* const* d_in, const int* in_sizes, int n_in,
                              void* d_out, int out_size, void* d_ws, size_t ws_size,
                              hipStream_t stream) {
    const int* adj    = (const int*)d_in[0];
    const float* vals = (const float*)d_in[1];
    const float* xs   = (const float*)d_in[2];
    const float* gw   = (const float*)d_in[3];
    const float* gb   = (const float*)d_in[4];
    const float* wih  = (const float*)d_in[5];
    const float* whh  = (const float*)d_in[6];
    const float* bih  = (const float*)d_in[7];
    const float* bhh  = (const float*)d_in[8];
    const float* h0   = (const float*)d_in[9];
    const float* c0   = (const float*)d_in[10];
    float* out = (float*)d_out;

    // Workspace layout (peak concurrent = 251,658,240 B):
    //   [0, 50,331,648)             cur (bf16, S*N*128)
    //   [50,331,648, 251,658,240)   gx  (bf16, S*N*512)
    // Aliased INSIDE the gx region (dead before k_xgates writes gx):
    //   support @ gx+0, counts/offs/cursor/edges after it.
    char* ws = (char*)d_ws;
    unsigned short* cur = (unsigned short*)(ws);
    unsigned short* gx  = (unsigned short*)(ws + 50331648);
    unsigned short* sup = (unsigned short*)(ws + 50331648);
    int* counts         = (int*)(ws + 100663296);
    int* offs           = (int*)(ws + 101449728);
    int* cursor         = (int*)(ws + 102236160);
    int2* edges         = (int2*)(ws + 103022592);

    k_zero<<<(SS * NN) / 256, 256, 0, stream>>>(counts);
    k_count<<<(SS * EE) / 256, 256, 0, stream>>>(adj, counts);
    k_scan<<<SS, 1024, 0, stream>>>(counts, offs, cursor);
    k_scatter<<<(SS * EE) / 256, 256, 0, stream>>>(adj, vals, cursor, edges);
    k_support<<<(SS * NN) / 64, 256, 0, stream>>>(xs, gw, sup);
    k_gather<<<(SS * NN) / 4, 256, 0, stream>>>(edges, offs, cursor, sup, gb, cur);
    k_xgates<<<dim3((SS * NN) / 64, 8), 256, 0, stream>>>(cur, wih, bih, bhh, gx);
    k_lstm<<<64, 512, 0, stream>>>(gx, whh, h0, c0, out);
}